// Round 1
// baseline (332.054 us; speedup 1.0000x reference)
//
#include <hip/hip_runtime.h>

// Instant-NGP style multiresolution hash-grid encode, forward only.
// One thread per (point, level): thread = point*16 + level.
//  - consecutive lanes -> consecutive float2 out writes (coalesced 512B/wave)
//  - 16 lanes share one point's xyz (L1 broadcast)
//  - 8 random float2 gathers per thread from a 4MB per-level table
//    (all 16 tables = 64 MB, L3-resident)

#define HG_N_LEVELS   16
#define HG_TABLE_SIZE 524288u
#define HG_TABLE_MASK (HG_TABLE_SIZE - 1u)

__global__ __launch_bounds__(256) void hashgrid_fwd(
    const float* __restrict__ xyz,
    const float* __restrict__ tables,
    const int*   __restrict__ resolutions,
    float*       __restrict__ out,
    int n_points)
{
    int tid   = blockIdx.x * blockDim.x + threadIdx.x;
    int point = tid >> 4;    // /16
    int level = tid & 15;
    if (point >= n_points) return;

    // --- bit-exact replication of the reference index math (fp32) ---
    float px = xyz[point * 3 + 0];
    float py = xyz[point * 3 + 1];
    float pz = xyz[point * 3 + 2];
    const float lim = 1.0f - 1e-6f;
    float ux = fminf(fmaxf(px + 0.5f, 0.0f), lim);
    float uy = fminf(fmaxf(py + 0.5f, 0.0f), lim);
    float uz = fminf(fmaxf(pz + 0.5f, 0.0f), lim);

    float res = (float)resolutions[level];
    float fx = ux * res, fy = uy * res, fz = uz * res;
    float x0f = floorf(fx), y0f = floorf(fy), z0f = floorf(fz);
    float wx1 = fx - x0f,  wy1 = fy - y0f,  wz1 = fz - z0f;
    float wx0 = 1.0f - wx1, wy0 = 1.0f - wy1, wz0 = 1.0f - wz1;
    unsigned x0 = (unsigned)x0f, y0 = (unsigned)y0f, z0 = (unsigned)z0f;

    const unsigned P1 = 2654435761u, P2 = 805459861u;  // PRIMES[1], PRIMES[2]; PRIMES[0]=1
    unsigned hx0 = x0;
    unsigned hx1 = x0 + 1u;
    unsigned hy0 = y0 * P1;
    unsigned hy1 = (y0 + 1u) * P1;
    unsigned hz0 = z0 * P2;
    unsigned hz1 = (z0 + 1u) * P2;

    // corner c: offs = ((c>>2)&1, (c>>1)&1, c&1) for (x,y,z)
    unsigned idx0 = (hx0 ^ hy0 ^ hz0) & HG_TABLE_MASK;
    unsigned idx1 = (hx0 ^ hy0 ^ hz1) & HG_TABLE_MASK;
    unsigned idx2 = (hx0 ^ hy1 ^ hz0) & HG_TABLE_MASK;
    unsigned idx3 = (hx0 ^ hy1 ^ hz1) & HG_TABLE_MASK;
    unsigned idx4 = (hx1 ^ hy0 ^ hz0) & HG_TABLE_MASK;
    unsigned idx5 = (hx1 ^ hy0 ^ hz1) & HG_TABLE_MASK;
    unsigned idx6 = (hx1 ^ hy1 ^ hz0) & HG_TABLE_MASK;
    unsigned idx7 = (hx1 ^ hy1 ^ hz1) & HG_TABLE_MASK;

    const float2* __restrict__ tbl =
        (const float2*)tables + (size_t)level * HG_TABLE_SIZE;

    // issue all 8 gathers before any use (ILP latency hiding)
    float2 f0 = tbl[idx0];
    float2 f1 = tbl[idx1];
    float2 f2 = tbl[idx2];
    float2 f3 = tbl[idx3];
    float2 f4 = tbl[idx4];
    float2 f5 = tbl[idx5];
    float2 f6 = tbl[idx6];
    float2 f7 = tbl[idx7];

    float w0 = wx0 * wy0 * wz0;
    float w1 = wx0 * wy0 * wz1;
    float w2 = wx0 * wy1 * wz0;
    float w3 = wx0 * wy1 * wz1;
    float w4 = wx1 * wy0 * wz0;
    float w5 = wx1 * wy0 * wz1;
    float w6 = wx1 * wy1 * wz0;
    float w7 = wx1 * wy1 * wz1;

    float o0 = w0 * f0.x + w1 * f1.x + w2 * f2.x + w3 * f3.x
             + w4 * f4.x + w5 * f5.x + w6 * f6.x + w7 * f7.x;
    float o1 = w0 * f0.y + w1 * f1.y + w2 * f2.y + w3 * f3.y
             + w4 * f4.y + w5 * f5.y + w6 * f6.y + w7 * f7.y;

    ((float2*)out)[(size_t)point * HG_N_LEVELS + level] = make_float2(o0, o1);
}

extern "C" void kernel_launch(void* const* d_in, const int* in_sizes, int n_in,
                              void* d_out, int out_size, void* d_ws, size_t ws_size,
                              hipStream_t stream) {
    const float* xyz         = (const float*)d_in[0];
    const float* tables      = (const float*)d_in[1];
    const int*   resolutions = (const int*)d_in[2];
    float*       out         = (float*)d_out;

    int n_points = in_sizes[0] / 3;
    int n_threads = n_points * HG_N_LEVELS;
    int block = 256;
    int grid = (n_threads + block - 1) / block;
    hashgrid_fwd<<<grid, block, 0, stream>>>(xyz, tables, resolutions, out, n_points);
}

// Round 3
// 271.264 us; speedup vs baseline: 1.2241x; 1.2241x over previous
//
#include <hip/hip_runtime.h>

// Instant-NGP hash-grid encode, two-phase XCD-pinned version.
//
// Phase 1 (hashgrid_gather_lvl): one block = one level (level = blockIdx&15).
//   HW dispatches blocks round-robin across the 8 XCDs (blockIdx%8), so level L
//   always lands on XCD L%8 -> each XCD's 4MiB L2 only serves tables {j, j+8}
//   (one small low-res + one 4MB capped table, <=8MB hot) instead of all 16
//   (~40MB hot). Output written level-major [16][N] float2 (coalesced, NT).
// Phase 2 (hashgrid_transpose): LDS-tiled [16][N] -> [N][16] transpose,
//   both sides coalesced. 64MB streaming traffic, ws is L3-resident.
//
// Falls back to the proven single-kernel version if ws_size < 32MB.

#define HG_N_LEVELS   16
#define HG_TABLE_SIZE 524288u
#define HG_TABLE_MASK (HG_TABLE_SIZE - 1u)

// native 2-float vector: __builtin_nontemporal_* accepts this (not HIP float2)
typedef float vf2 __attribute__((ext_vector_type(2)));

__device__ __forceinline__ void hg_interp(
    float px, float py, float pz, float res,
    const float2* __restrict__ tbl, float2* out_val)
{
    const float lim = 1.0f - 1e-6f;
    float ux = fminf(fmaxf(px + 0.5f, 0.0f), lim);
    float uy = fminf(fmaxf(py + 0.5f, 0.0f), lim);
    float uz = fminf(fmaxf(pz + 0.5f, 0.0f), lim);

    float fx = ux * res, fy = uy * res, fz = uz * res;
    float x0f = floorf(fx), y0f = floorf(fy), z0f = floorf(fz);
    float wx1 = fx - x0f,  wy1 = fy - y0f,  wz1 = fz - z0f;
    float wx0 = 1.0f - wx1, wy0 = 1.0f - wy1, wz0 = 1.0f - wz1;
    unsigned x0 = (unsigned)x0f, y0 = (unsigned)y0f, z0 = (unsigned)z0f;

    const unsigned P1 = 2654435761u, P2 = 805459861u;
    unsigned hx0 = x0,            hx1 = x0 + 1u;
    unsigned hy0 = y0 * P1,       hy1 = (y0 + 1u) * P1;
    unsigned hz0 = z0 * P2,       hz1 = (z0 + 1u) * P2;

    unsigned idx0 = (hx0 ^ hy0 ^ hz0) & HG_TABLE_MASK;
    unsigned idx1 = (hx0 ^ hy0 ^ hz1) & HG_TABLE_MASK;
    unsigned idx2 = (hx0 ^ hy1 ^ hz0) & HG_TABLE_MASK;
    unsigned idx3 = (hx0 ^ hy1 ^ hz1) & HG_TABLE_MASK;
    unsigned idx4 = (hx1 ^ hy0 ^ hz0) & HG_TABLE_MASK;
    unsigned idx5 = (hx1 ^ hy0 ^ hz1) & HG_TABLE_MASK;
    unsigned idx6 = (hx1 ^ hy1 ^ hz0) & HG_TABLE_MASK;
    unsigned idx7 = (hx1 ^ hy1 ^ hz1) & HG_TABLE_MASK;

    float2 f0 = tbl[idx0];
    float2 f1 = tbl[idx1];
    float2 f2 = tbl[idx2];
    float2 f3 = tbl[idx3];
    float2 f4 = tbl[idx4];
    float2 f5 = tbl[idx5];
    float2 f6 = tbl[idx6];
    float2 f7 = tbl[idx7];

    float w0 = wx0 * wy0 * wz0;
    float w1 = wx0 * wy0 * wz1;
    float w2 = wx0 * wy1 * wz0;
    float w3 = wx0 * wy1 * wz1;
    float w4 = wx1 * wy0 * wz0;
    float w5 = wx1 * wy0 * wz1;
    float w6 = wx1 * wy1 * wz0;
    float w7 = wx1 * wy1 * wz1;

    out_val->x = w0 * f0.x + w1 * f1.x + w2 * f2.x + w3 * f3.x
               + w4 * f4.x + w5 * f5.x + w6 * f6.x + w7 * f7.x;
    out_val->y = w0 * f0.y + w1 * f1.y + w2 * f2.y + w3 * f3.y
               + w4 * f4.y + w5 * f5.y + w6 * f6.y + w7 * f7.y;
}

// ---------- Phase 1: level-pinned gather -> ws [16][N] float2 ----------
__global__ __launch_bounds__(256) void hashgrid_gather_lvl(
    const float* __restrict__ xyz,
    const float* __restrict__ tables,
    const int*   __restrict__ resolutions,
    float2*      __restrict__ ws,
    int n_points)
{
    const int level = blockIdx.x & 15;       // wave-uniform -> SGPR
    const int chunk = blockIdx.x >> 4;
    const float res = (float)resolutions[level];
    const float2* __restrict__ tbl =
        (const float2*)tables + (size_t)level * HG_TABLE_SIZE;
    float2* __restrict__ wlev = ws + (size_t)level * n_points;

    #pragma unroll
    for (int it = 0; it < 4; ++it) {
        int point = chunk * 1024 + it * 256 + (int)threadIdx.x;
        if (point >= n_points) return;
        // NT loads: xyz must not evict pinned table lines from this XCD's L2
        float px = __builtin_nontemporal_load(xyz + (size_t)point * 3 + 0);
        float py = __builtin_nontemporal_load(xyz + (size_t)point * 3 + 1);
        float pz = __builtin_nontemporal_load(xyz + (size_t)point * 3 + 2);
        float2 v;
        hg_interp(px, py, pz, res, tbl, &v);
        vf2 vv; vv.x = v.x; vv.y = v.y;
        __builtin_nontemporal_store(vv, (vf2*)(wlev + point));  // coalesced, streaming
    }
}

// ---------- Phase 2: transpose ws [16][N] -> out [N][16] (float2 elems) ----------
__global__ __launch_bounds__(256) void hashgrid_transpose(
    const float2* __restrict__ ws,
    float2*       __restrict__ out,
    int n_points)
{
    __shared__ float2 tile[256 * 17];        // [pt][lev], +1 pad
    const int p0 = blockIdx.x * 256;
    const int tid = threadIdx.x;

    #pragma unroll
    for (int r = 0; r < 16; ++r) {           // read: level-major, coalesced
        int lev = r;
        int pt  = tid;
        int point = p0 + pt;
        if (point < n_points) {
            vf2 v = __builtin_nontemporal_load(
                (const vf2*)(ws + (size_t)lev * n_points + point));
            tile[pt * 17 + lev] = make_float2(v.x, v.y);
        }
    }
    __syncthreads();
    #pragma unroll
    for (int r = 0; r < 16; ++r) {           // write: point-major, coalesced
        int e   = r * 256 + tid;
        int pt  = e >> 4;
        int lev = e & 15;
        int point = p0 + pt;
        if (point < n_points) {
            float2 t = tile[pt * 17 + lev];
            vf2 v; v.x = t.x; v.y = t.y;
            __builtin_nontemporal_store(
                v, (vf2*)(out + (size_t)point * HG_N_LEVELS + lev));
        }
    }
}

// ---------- Fallback: proven single-kernel version (round 1) ----------
__global__ __launch_bounds__(256) void hashgrid_fwd(
    const float* __restrict__ xyz,
    const float* __restrict__ tables,
    const int*   __restrict__ resolutions,
    float*       __restrict__ out,
    int n_points)
{
    int tid   = blockIdx.x * blockDim.x + threadIdx.x;
    int point = tid >> 4;
    int level = tid & 15;
    if (point >= n_points) return;

    float px = xyz[point * 3 + 0];
    float py = xyz[point * 3 + 1];
    float pz = xyz[point * 3 + 2];
    float res = (float)resolutions[level];
    const float2* __restrict__ tbl =
        (const float2*)tables + (size_t)level * HG_TABLE_SIZE;
    float2 v;
    hg_interp(px, py, pz, res, tbl, &v);
    ((float2*)out)[(size_t)point * HG_N_LEVELS + level] = v;
}

extern "C" void kernel_launch(void* const* d_in, const int* in_sizes, int n_in,
                              void* d_out, int out_size, void* d_ws, size_t ws_size,
                              hipStream_t stream) {
    const float* xyz         = (const float*)d_in[0];
    const float* tables      = (const float*)d_in[1];
    const int*   resolutions = (const int*)d_in[2];
    float*       out         = (float*)d_out;

    int n_points = in_sizes[0] / 3;
    size_t ws_needed = (size_t)n_points * HG_N_LEVELS * sizeof(float2);

    if (ws_size >= ws_needed) {
        float2* ws = (float2*)d_ws;
        int chunks = (n_points + 1023) / 1024;
        hashgrid_gather_lvl<<<chunks * 16, 256, 0, stream>>>(
            xyz, tables, resolutions, ws, n_points);
        int tblocks = (n_points + 255) / 256;
        hashgrid_transpose<<<tblocks, 256, 0, stream>>>(
            ws, (float2*)out, n_points);
    } else {
        int n_threads = n_points * HG_N_LEVELS;
        hashgrid_fwd<<<(n_threads + 255) / 256, 256, 0, stream>>>(
            xyz, tables, resolutions, out, n_points);
    }
}

// Round 4
// 250.080 us; speedup vs baseline: 1.3278x; 1.0847x over previous
//
#include <hip/hip_runtime.h>

// Instant-NGP hash-grid encode, two-phase, XCD-pinned with balanced schedule.
//
// Phase 1 (hashgrid_gather_lvl): XCD x = blockIdx%8. Static schedule:
//   - slow levels 8..15 (4MB table working set): level 8+x pinned to XCD x
//   - level 7 (also 4MB): chunks round-robin over all 8 XCDs
//   - level 6 (2.2MB): split over XCDs {6,7}
//   - levels 0..5 (tiny): XCD = level
//   -> max per-XCD load ~1.28 slow-units (was 2.0 with level=blockIdx&15),
//      per-XCD L2 hot set stays ~1 big table + shares.
//   2 points/thread, 16 gathers in flight (2x MLP vs round 3).
//   Output level-major ws[16][N] float2, NT stores (don't evict tables).
// Phase 2 (hashgrid_transpose): float4-wide LDS transpose [16][N]->[N][16],
//   cached loads (ws is L3-resident), NT float4 stores.

#define HG_N_LEVELS   16
#define HG_TABLE_SIZE 524288u
#define HG_TABLE_MASK (HG_TABLE_SIZE - 1u)

typedef float vf2 __attribute__((ext_vector_type(2)));
typedef float vf4 __attribute__((ext_vector_type(4)));

__device__ __forceinline__ void hg_prep(
    float px, float py, float pz, float res,
    unsigned* __restrict__ idx, float* __restrict__ w)
{
    const float lim = 1.0f - 1e-6f;
    float ux = fminf(fmaxf(px + 0.5f, 0.0f), lim);
    float uy = fminf(fmaxf(py + 0.5f, 0.0f), lim);
    float uz = fminf(fmaxf(pz + 0.5f, 0.0f), lim);
    float fx = ux * res, fy = uy * res, fz = uz * res;
    float x0f = floorf(fx), y0f = floorf(fy), z0f = floorf(fz);
    float wx1 = fx - x0f, wy1 = fy - y0f, wz1 = fz - z0f;
    float wx0 = 1.0f - wx1, wy0 = 1.0f - wy1, wz0 = 1.0f - wz1;
    unsigned x0 = (unsigned)x0f, y0 = (unsigned)y0f, z0 = (unsigned)z0f;
    const unsigned P1 = 2654435761u, P2 = 805459861u;
    unsigned hx0 = x0,      hx1 = x0 + 1u;
    unsigned hy0 = y0 * P1, hy1 = (y0 + 1u) * P1;
    unsigned hz0 = z0 * P2, hz1 = (z0 + 1u) * P2;
    idx[0] = (hx0 ^ hy0 ^ hz0) & HG_TABLE_MASK;  w[0] = wx0 * wy0 * wz0;
    idx[1] = (hx0 ^ hy0 ^ hz1) & HG_TABLE_MASK;  w[1] = wx0 * wy0 * wz1;
    idx[2] = (hx0 ^ hy1 ^ hz0) & HG_TABLE_MASK;  w[2] = wx0 * wy1 * wz0;
    idx[3] = (hx0 ^ hy1 ^ hz1) & HG_TABLE_MASK;  w[3] = wx0 * wy1 * wz1;
    idx[4] = (hx1 ^ hy0 ^ hz0) & HG_TABLE_MASK;  w[4] = wx1 * wy0 * wz0;
    idx[5] = (hx1 ^ hy0 ^ hz1) & HG_TABLE_MASK;  w[5] = wx1 * wy0 * wz1;
    idx[6] = (hx1 ^ hy1 ^ hz0) & HG_TABLE_MASK;  w[6] = wx1 * wy1 * wz0;
    idx[7] = (hx1 ^ hy1 ^ hz1) & HG_TABLE_MASK;  w[7] = wx1 * wy1 * wz1;
}

// ---------- Phase 1: balanced level-pinned gather -> ws [16][N] float2 ----------
__global__ __launch_bounds__(256) void hashgrid_gather_lvl(
    const float* __restrict__ xyz,
    const float* __restrict__ tables,
    const int*   __restrict__ resolutions,
    float*       __restrict__ ws,       // [16][n] float2, as floats
    int n_points)
{
    const int x    = blockIdx.x & 7;    // XCD (blockIdx%8 round-robin)
    const int slot = blockIdx.x >> 3;   // position in XCD x's work queue
    const int C    = (n_points + 511) >> 9;  // 512-point chunks per level
    const int C8   = (C + 7) >> 3;

    int level, chunk;
    if (slot < C)            { level = 8 + x; chunk = slot; }
    else if (slot < C + C8)  { int j = slot - C; level = 7; chunk = x + (j << 3); }
    else                     { int j = slot - C - C8;
                               if (x >= 6) { level = 6; chunk = (x - 6) + (j << 1); }
                               else        { level = x; chunk = j; } }
    if (chunk >= C) return;

    const float res = (float)resolutions[level];
    const float2* __restrict__ tbl =
        (const float2*)tables + (size_t)level * HG_TABLE_SIZE;
    float* __restrict__ wlev = ws + (size_t)level * n_points * 2;

    const int p0 = (chunk << 9) + ((int)threadIdx.x << 1);   // 2 pts/thread
    if (p0 >= n_points) return;
    const bool has1 = (p0 + 1) < n_points;

    float axp, ayp, azp, bxp, byp, bzp;
    const float* xp = xyz + (size_t)p0 * 3;     // byte offset 24*t: 8-aligned
    if (has1) {
        vf2 c0 = *(const vf2*)(xp);
        vf2 c1 = *(const vf2*)(xp + 2);
        vf2 c2 = *(const vf2*)(xp + 4);
        axp = c0.x; ayp = c0.y; azp = c1.x;
        bxp = c1.y; byp = c2.x; bzp = c2.y;
    } else {
        axp = xp[0]; ayp = xp[1]; azp = xp[2];
        bxp = axp; byp = ayp; bzp = azp;
    }

    unsigned ia[8], ib[8]; float wa[8], wb[8];
    hg_prep(axp, ayp, azp, res, ia, wa);
    hg_prep(bxp, byp, bzp, res, ib, wb);

    // issue all 16 gathers before any use (MLP=16)
    vf2 fa[8], fb[8];
    #pragma unroll
    for (int k = 0; k < 8; ++k) fa[k] = *(const vf2*)(tbl + ia[k]);
    #pragma unroll
    for (int k = 0; k < 8; ++k) fb[k] = *(const vf2*)(tbl + ib[k]);

    float oax = 0.f, oay = 0.f, obx = 0.f, oby = 0.f;
    #pragma unroll
    for (int k = 0; k < 8; ++k) { oax += wa[k] * fa[k].x; oay += wa[k] * fa[k].y; }
    #pragma unroll
    for (int k = 0; k < 8; ++k) { obx += wb[k] * fb[k].x; oby += wb[k] * fb[k].y; }

    if (has1) {
        vf4 v; v.x = oax; v.y = oay; v.z = obx; v.w = oby;
        __builtin_nontemporal_store(v, (vf4*)(wlev + 2 * (size_t)p0)); // 16B aligned
    } else {
        vf2 v; v.x = oax; v.y = oay;
        __builtin_nontemporal_store(v, (vf2*)(wlev + 2 * (size_t)p0));
    }
}

// ---------- Phase 2: transpose ws [16][N] -> out [N][16], float4 both sides ----------
#define TP_PTS 256
#define TP_STRIDE (2 * TP_PTS + 4)   // floats per LDS row (pad 4 -> <=2-way conflicts)

__global__ __launch_bounds__(256) void hashgrid_transpose(
    const float* __restrict__ ws,
    float*       __restrict__ out,
    int n_points)
{
    __shared__ float tile[16 * TP_STRIDE];   // ~33 KB, level-major
    const int p0 = blockIdx.x * TP_PTS;
    const int t  = (int)threadIdx.x;
    const int npts = min(TP_PTS, n_points - p0);

    // load: 16 rows x 512 floats; per iter 2 rows x 128 vf4 (cached loads)
    #pragma unroll
    for (int it = 0; it < 8; ++it) {
        int r  = it * 2 + (t >> 7);
        int q  = t & 127;
        int pt = q * 2;
        if (pt < npts) {
            const float* src = ws + (size_t)r * n_points * 2 + (size_t)(p0 + pt) * 2;
            vf4 v;
            if (pt + 1 < npts) v = *(const vf4*)src;          // 16B aligned
            else { vf2 v2 = *(const vf2*)src; v.x = v2.x; v.y = v2.y; v.z = 0.f; v.w = 0.f; }
            *(vf4*)&tile[r * TP_STRIDE + 4 * q] = v;          // 16B LDS write
        }
    }
    __syncthreads();

    // store: per point 32 floats = 8 vf4; 256 pts x 8 vf4 / 256 thr = 8 iters
    #pragma unroll
    for (int it = 0; it < 8; ++it) {
        int linear = it * 256 + t;
        int pt = linear >> 3;
        int v4 = linear & 7;
        if (pt < npts) {
            vf4 v;
            #pragma unroll
            for (int k = 0; k < 4; ++k) {
                int e = 4 * v4 + k;          // float index within point's 32
                int lev = e >> 1, f = e & 1;
                v[k] = tile[lev * TP_STRIDE + 2 * pt + f];
            }
            __builtin_nontemporal_store(
                v, (vf4*)(out + (size_t)(p0 + pt) * 32 + 4 * v4));
        }
    }
}

// ---------- Fallback: single-kernel version (round 1 structure) ----------
__global__ __launch_bounds__(256) void hashgrid_fwd(
    const float* __restrict__ xyz,
    const float* __restrict__ tables,
    const int*   __restrict__ resolutions,
    float*       __restrict__ out,
    int n_points)
{
    int tid   = blockIdx.x * blockDim.x + threadIdx.x;
    int point = tid >> 4;
    int level = tid & 15;
    if (point >= n_points) return;

    float px = xyz[point * 3 + 0];
    float py = xyz[point * 3 + 1];
    float pz = xyz[point * 3 + 2];
    float res = (float)resolutions[level];
    const float2* __restrict__ tbl =
        (const float2*)tables + (size_t)level * HG_TABLE_SIZE;

    unsigned idx[8]; float w[8];
    hg_prep(px, py, pz, res, idx, w);
    vf2 f[8];
    #pragma unroll
    for (int k = 0; k < 8; ++k) f[k] = *(const vf2*)(tbl + idx[k]);
    float ox = 0.f, oy = 0.f;
    #pragma unroll
    for (int k = 0; k < 8; ++k) { ox += w[k] * f[k].x; oy += w[k] * f[k].y; }
    vf2 v; v.x = ox; v.y = oy;
    *(vf2*)(out + (size_t)point * 32 + 2 * level) = v;
}

extern "C" void kernel_launch(void* const* d_in, const int* in_sizes, int n_in,
                              void* d_out, int out_size, void* d_ws, size_t ws_size,
                              hipStream_t stream) {
    const float* xyz         = (const float*)d_in[0];
    const float* tables      = (const float*)d_in[1];
    const int*   resolutions = (const int*)d_in[2];
    float*       out         = (float*)d_out;

    int n_points = in_sizes[0] / 3;
    size_t ws_needed = (size_t)n_points * HG_N_LEVELS * sizeof(float2);

    if (ws_size >= ws_needed) {
        float* ws = (float*)d_ws;
        int C  = (n_points + 511) >> 9;
        int C8 = (C + 7) >> 3;
        int slots = 2 * C + C8;
        hashgrid_gather_lvl<<<8 * slots, 256, 0, stream>>>(
            xyz, tables, resolutions, ws, n_points);
        int tblocks = (n_points + TP_PTS - 1) / TP_PTS;
        hashgrid_transpose<<<tblocks, 256, 0, stream>>>(ws, out, n_points);
    } else {
        int n_threads = n_points * HG_N_LEVELS;
        hashgrid_fwd<<<(n_threads + 255) / 256, 256, 0, stream>>>(
            xyz, tables, resolutions, out, n_points);
    }
}

// Round 6
// 231.918 us; speedup vs baseline: 1.4318x; 1.0783x over previous
//
#include <hip/hip_runtime.h>

// Instant-NGP hash-grid encode, two-phase, XCD-pinned, forced-MLP gathers.
//
// Phase 1 (hashgrid_gather_lvl): XCD x = blockIdx%8, balanced static schedule
//   (slow levels 8..15 pinned 1/XCD; level 7 round-robins all XCDs; level 6
//   split over XCDs 6,7; levels 0..5 -> XCD=level). 2 points/thread; all 16
//   table gathers are issued as plain loads, then pinned simultaneously live
//   via an empty asm with 16 "+v" operands + memory clobber. Round-4 evidence
//   (VGPR_Count=20) showed the compiler otherwise sinks loads into the FMA
//   loop, cutting per-wave MLP to ~4; this forces true MLP=16 while keeping
//   compiler-managed waitcnt (no raw load asm -- round 5's fault).
// Phase 2 (hashgrid_transpose): float4 LDS transpose ws[16][N] -> out[N][16].

#define HG_N_LEVELS   16
#define HG_TABLE_SIZE 524288u
#define HG_TABLE_MASK (HG_TABLE_SIZE - 1u)

typedef float vf2 __attribute__((ext_vector_type(2)));
typedef float vf4 __attribute__((ext_vector_type(4)));

__device__ __forceinline__ void hg_prep(
    float px, float py, float pz, float res,
    unsigned* __restrict__ idx, float* __restrict__ w)
{
    const float lim = 1.0f - 1e-6f;
    float ux = fminf(fmaxf(px + 0.5f, 0.0f), lim);
    float uy = fminf(fmaxf(py + 0.5f, 0.0f), lim);
    float uz = fminf(fmaxf(pz + 0.5f, 0.0f), lim);
    float fx = ux * res, fy = uy * res, fz = uz * res;
    float x0f = floorf(fx), y0f = floorf(fy), z0f = floorf(fz);
    float wx1 = fx - x0f, wy1 = fy - y0f, wz1 = fz - z0f;
    float wx0 = 1.0f - wx1, wy0 = 1.0f - wy1, wz0 = 1.0f - wz1;
    unsigned x0 = (unsigned)x0f, y0 = (unsigned)y0f, z0 = (unsigned)z0f;
    const unsigned P1 = 2654435761u, P2 = 805459861u;
    unsigned hx0 = x0,      hx1 = x0 + 1u;
    unsigned hy0 = y0 * P1, hy1 = (y0 + 1u) * P1;
    unsigned hz0 = z0 * P2, hz1 = (z0 + 1u) * P2;
    idx[0] = (hx0 ^ hy0 ^ hz0) & HG_TABLE_MASK;  w[0] = wx0 * wy0 * wz0;
    idx[1] = (hx0 ^ hy0 ^ hz1) & HG_TABLE_MASK;  w[1] = wx0 * wy0 * wz1;
    idx[2] = (hx0 ^ hy1 ^ hz0) & HG_TABLE_MASK;  w[2] = wx0 * wy1 * wz0;
    idx[3] = (hx0 ^ hy1 ^ hz1) & HG_TABLE_MASK;  w[3] = wx0 * wy1 * wz1;
    idx[4] = (hx1 ^ hy0 ^ hz0) & HG_TABLE_MASK;  w[4] = wx1 * wy0 * wz0;
    idx[5] = (hx1 ^ hy0 ^ hz1) & HG_TABLE_MASK;  w[5] = wx1 * wy0 * wz1;
    idx[6] = (hx1 ^ hy1 ^ hz0) & HG_TABLE_MASK;  w[6] = wx1 * wy1 * wz0;
    idx[7] = (hx1 ^ hy1 ^ hz1) & HG_TABLE_MASK;  w[7] = wx1 * wy1 * wz1;
}

// ---------- Phase 1: balanced level-pinned gather -> ws [16][N] float2 ----------
__global__ __launch_bounds__(256) void hashgrid_gather_lvl(
    const float* __restrict__ xyz,
    const float* __restrict__ tables,
    const int*   __restrict__ resolutions,
    float*       __restrict__ ws,       // [16][n] float2, as floats
    int n_points)
{
    const int x    = blockIdx.x & 7;    // XCD (blockIdx%8 round-robin)
    const int slot = blockIdx.x >> 3;   // position in XCD x's work queue
    const int C    = (n_points + 511) >> 9;  // 512-point chunks per level
    const int C8   = (C + 7) >> 3;

    int level, chunk;
    if (slot < C)            { level = 8 + x; chunk = slot; }
    else if (slot < C + C8)  { int j = slot - C; level = 7; chunk = x + (j << 3); }
    else                     { int j = slot - C - C8;
                               if (x >= 6) { level = 6; chunk = (x - 6) + (j << 1); }
                               else        { level = x; chunk = j; } }
    if (chunk >= C) return;

    const float res = (float)resolutions[level];
    const float2* __restrict__ tbl =
        (const float2*)tables + (size_t)level * HG_TABLE_SIZE;
    float* __restrict__ wlev = ws + (size_t)level * n_points * 2;

    const int p0 = (chunk << 9) + ((int)threadIdx.x << 1);   // 2 pts/thread
    if (p0 >= n_points) return;
    const bool has1 = (p0 + 1) < n_points;

    float axp, ayp, azp, bxp, byp, bzp;
    const float* xp = xyz + (size_t)p0 * 3;     // 24B/thread: 8-aligned
    if (has1) {
        vf2 c0 = *(const vf2*)(xp);
        vf2 c1 = *(const vf2*)(xp + 2);
        vf2 c2 = *(const vf2*)(xp + 4);
        axp = c0.x; ayp = c0.y; azp = c1.x;
        bxp = c1.y; byp = c2.x; bzp = c2.y;
    } else {
        axp = xp[0]; ayp = xp[1]; azp = xp[2];
        bxp = axp; byp = ayp; bzp = azp;
    }

    unsigned ia[8], ib[8]; float wa[8], wb[8];
    hg_prep(axp, ayp, azp, res, ia, wa);
    hg_prep(bxp, byp, bzp, res, ib, wb);

    // issue all 16 gathers (plain loads, compiler-managed waitcnt)
    vf2 fa[8], fb[8];
    #pragma unroll
    for (int k = 0; k < 8; ++k) fa[k] = *(const vf2*)(tbl + ia[k]);
    #pragma unroll
    for (int k = 0; k < 8; ++k) fb[k] = *(const vf2*)(tbl + ib[k]);

    // Pin all 16 results live at this point: loads cannot sink below the
    // memory clobber, uses cannot hoist above (they consume the asm outputs).
    // -> true per-wave MLP of 16.
    asm volatile(""
        : "+v"(fa[0]), "+v"(fa[1]), "+v"(fa[2]), "+v"(fa[3]),
          "+v"(fa[4]), "+v"(fa[5]), "+v"(fa[6]), "+v"(fa[7]),
          "+v"(fb[0]), "+v"(fb[1]), "+v"(fb[2]), "+v"(fb[3]),
          "+v"(fb[4]), "+v"(fb[5]), "+v"(fb[6]), "+v"(fb[7])
        :
        : "memory");

    float oax = 0.f, oay = 0.f, obx = 0.f, oby = 0.f;
    #pragma unroll
    for (int k = 0; k < 8; ++k) { oax += wa[k] * fa[k].x; oay += wa[k] * fa[k].y; }
    #pragma unroll
    for (int k = 0; k < 8; ++k) { obx += wb[k] * fb[k].x; oby += wb[k] * fb[k].y; }

    if (has1) {
        vf4 v; v.x = oax; v.y = oay; v.z = obx; v.w = oby;
        __builtin_nontemporal_store(v, (vf4*)(wlev + 2 * (size_t)p0)); // 16B aligned
    } else {
        vf2 v; v.x = oax; v.y = oay;
        __builtin_nontemporal_store(v, (vf2*)(wlev + 2 * (size_t)p0));
    }
}

// ---------- Phase 2: transpose ws [16][N] -> out [N][16], float4 both sides ----------
#define TP_PTS 256
#define TP_STRIDE (2 * TP_PTS + 4)   // floats per LDS row (pad 4 -> <=2-way conflicts)

__global__ __launch_bounds__(256) void hashgrid_transpose(
    const float* __restrict__ ws,
    float*       __restrict__ out,
    int n_points)
{
    __shared__ float tile[16 * TP_STRIDE];   // ~33 KB, level-major
    const int p0 = blockIdx.x * TP_PTS;
    const int t  = (int)threadIdx.x;
    const int npts = min(TP_PTS, n_points - p0);

    #pragma unroll
    for (int it = 0; it < 8; ++it) {
        int r  = it * 2 + (t >> 7);
        int q  = t & 127;
        int pt = q * 2;
        if (pt < npts) {
            const float* src = ws + (size_t)r * n_points * 2 + (size_t)(p0 + pt) * 2;
            vf4 v;
            if (pt + 1 < npts) v = *(const vf4*)src;
            else { vf2 v2 = *(const vf2*)src; v.x = v2.x; v.y = v2.y; v.z = 0.f; v.w = 0.f; }
            *(vf4*)&tile[r * TP_STRIDE + 4 * q] = v;
        }
    }
    __syncthreads();

    #pragma unroll
    for (int it = 0; it < 8; ++it) {
        int linear = it * 256 + t;
        int pt = linear >> 3;
        int v4 = linear & 7;
        if (pt < npts) {
            vf4 v;
            #pragma unroll
            for (int k = 0; k < 4; ++k) {
                int e = 4 * v4 + k;
                int lev = e >> 1, f = e & 1;
                v[k] = tile[lev * TP_STRIDE + 2 * pt + f];
            }
            __builtin_nontemporal_store(
                v, (vf4*)(out + (size_t)(p0 + pt) * 32 + 4 * v4));
        }
    }
}

// ---------- Fallback: single-kernel version ----------
__global__ __launch_bounds__(256) void hashgrid_fwd(
    const float* __restrict__ xyz,
    const float* __restrict__ tables,
    const int*   __restrict__ resolutions,
    float*       __restrict__ out,
    int n_points)
{
    int tid   = blockIdx.x * blockDim.x + threadIdx.x;
    int point = tid >> 4;
    int level = tid & 15;
    if (point >= n_points) return;

    float px = xyz[point * 3 + 0];
    float py = xyz[point * 3 + 1];
    float pz = xyz[point * 3 + 2];
    float res = (float)resolutions[level];
    const float2* __restrict__ tbl =
        (const float2*)tables + (size_t)level * HG_TABLE_SIZE;

    unsigned idx[8]; float w[8];
    hg_prep(px, py, pz, res, idx, w);
    vf2 f[8];
    #pragma unroll
    for (int k = 0; k < 8; ++k) f[k] = *(const vf2*)(tbl + idx[k]);
    float ox = 0.f, oy = 0.f;
    #pragma unroll
    for (int k = 0; k < 8; ++k) { ox += w[k] * f[k].x; oy += w[k] * f[k].y; }
    vf2 v; v.x = ox; v.y = oy;
    *(vf2*)(out + (size_t)point * 32 + 2 * level) = v;
}

extern "C" void kernel_launch(void* const* d_in, const int* in_sizes, int n_in,
                              void* d_out, int out_size, void* d_ws, size_t ws_size,
                              hipStream_t stream) {
    const float* xyz         = (const float*)d_in[0];
    const float* tables      = (const float*)d_in[1];
    const int*   resolutions = (const int*)d_in[2];
    float*       out         = (float*)d_out;

    int n_points = in_sizes[0] / 3;
    size_t ws_needed = (size_t)n_points * HG_N_LEVELS * sizeof(float2);

    if (ws_size >= ws_needed) {
        float* ws = (float*)d_ws;
        int C  = (n_points + 511) >> 9;
        int C8 = (C + 7) >> 3;
        int slots = 2 * C + C8;          // covers the longest XCD queue
        hashgrid_gather_lvl<<<8 * slots, 256, 0, stream>>>(
            xyz, tables, resolutions, ws, n_points);
        int tblocks = (n_points + TP_PTS - 1) / TP_PTS;
        hashgrid_transpose<<<tblocks, 256, 0, stream>>>(ws, out, n_points);
    } else {
        int n_threads = n_points * HG_N_LEVELS;
        hashgrid_fwd<<<(n_threads + 255) / 256, 256, 0, stream>>>(
            xyz, tables, resolutions, out, n_points);
    }
}